// Round 4
// baseline (243.474 us; speedup 1.0000x reference)
//
#include <hip/hip_runtime.h>

// CSPN propagation step, row-per-wave, register-only (no stack arrays).
// out[b,0,y,x] = sum_{k!=4} aff[b,k,y,x]*cur[b,0,y+dy-1,x+dx-1] (zero pad)
//              + aff[b,4,y,x]*coarse[b,0,y,x],   k = dy*3+dx.
//
// W=512 = 64 lanes * 8 px: one wave per row. x-halos via __shfl; shifted
// 8-wide windows via __builtin_shufflevector (register renames, no scratch).

typedef float f8 __attribute__((ext_vector_type(8)));

constexpr int Bc = 16, Hc = 512, Wc = 512;

__global__ __launch_bounds__(256) void cspn_kernel(
    const float* __restrict__ aff,
    const float* __restrict__ cur,
    const float* __restrict__ coarse,
    float* __restrict__ out)
{
    const int lane  = threadIdx.x & 63;
    const int row   = (blockIdx.x << 2) + (threadIdx.x >> 6);  // 0..B*H-1
    const int y     = row & (Hc - 1);
    const int b     = row >> 9;                                // row / H
    const int plane = Hc * Wc;
    const int rb    = row * Wc;                                // b*plane + y*W
    const int xo    = lane << 3;                               // 8 px per lane

    const float* curp = cur + rb + xo;

    // Source rows (zero at y borders; wave-uniform branches)
    f8 mm = *(const f8*)curp;
    f8 um = (f8)(0.f), dm = (f8)(0.f);
    if (y > 0)      um = *(const f8*)(curp - Wc);
    if (y < Hc - 1) dm = *(const f8*)(curp + Wc);
    f8 cm = *(const f8*)(coarse + rb + xo);

    // x-halos from neighbor lanes (zero at image borders)
    float uL = __shfl_up(um.s7, 1), mL = __shfl_up(mm.s7, 1), dL = __shfl_up(dm.s7, 1);
    float uR = __shfl_down(um.s0, 1), mR = __shfl_down(mm.s0, 1), dR = __shfl_down(dm.s0, 1);
    if (lane == 0)  { uL = 0.f; mL = 0.f; dL = 0.f; }
    if (lane == 63) { uR = 0.f; mR = 0.f; dR = 0.f; }

    // Shifted windows, all in registers: l = [halo, v0..v6], r = [v1..v7, halo]
    f8 ul = __builtin_shufflevector(um, um, 7,0,1,2,3,4,5,6); ul.s0 = uL;
    f8 ml = __builtin_shufflevector(mm, mm, 7,0,1,2,3,4,5,6); ml.s0 = mL;
    f8 dl = __builtin_shufflevector(dm, dm, 7,0,1,2,3,4,5,6); dl.s0 = dL;
    f8 ur = __builtin_shufflevector(um, um, 1,2,3,4,5,6,7,0); ur.s7 = uR;
    f8 mr = __builtin_shufflevector(mm, mm, 1,2,3,4,5,6,7,0); mr.s7 = mR;
    f8 dr = __builtin_shufflevector(dm, dm, 1,2,3,4,5,6,7,0); dr.s7 = dR;

    // 9 affinity channels (read-once -> nontemporal), FMA into acc
    const float* ab = aff + b * 9 * plane + y * Wc + xo;
    f8 a0 = __builtin_nontemporal_load((const f8*)(ab + 0 * plane));
    f8 a1 = __builtin_nontemporal_load((const f8*)(ab + 1 * plane));
    f8 a2 = __builtin_nontemporal_load((const f8*)(ab + 2 * plane));
    f8 a3 = __builtin_nontemporal_load((const f8*)(ab + 3 * plane));
    f8 a4 = __builtin_nontemporal_load((const f8*)(ab + 4 * plane));
    f8 a5 = __builtin_nontemporal_load((const f8*)(ab + 5 * plane));
    f8 a6 = __builtin_nontemporal_load((const f8*)(ab + 6 * plane));
    f8 a7 = __builtin_nontemporal_load((const f8*)(ab + 7 * plane));
    f8 a8 = __builtin_nontemporal_load((const f8*)(ab + 8 * plane));

    f8 acc = a0 * ul;
    acc += a1 * um;
    acc += a2 * ur;
    acc += a3 * ml;
    acc += a4 * cm;   // center tap -> coarse_seg
    acc += a5 * mr;
    acc += a6 * dl;
    acc += a7 * dm;
    acc += a8 * dr;

    __builtin_nontemporal_store(acc, (f8*)(out + rb + xo));
}

extern "C" void kernel_launch(void* const* d_in, const int* in_sizes, int n_in,
                              void* d_out, int out_size, void* d_ws, size_t ws_size,
                              hipStream_t stream) {
    const float* aff    = (const float*)d_in[0];  // [16, 9, 512, 512]
    const float* cur    = (const float*)d_in[1];  // [16, 1, 512, 512]
    const float* coarse = (const float*)d_in[2];  // [16, 1, 512, 512]
    float* out = (float*)d_out;                   // [16, 1, 512, 512]

    const int rows  = Bc * Hc;      // 8192 rows, one wave each
    const int block = 256;          // 4 waves per block
    const int grid  = rows / 4;     // 2048 blocks

    cspn_kernel<<<grid, block, 0, stream>>>(aff, cur, coarse, out);
}

// Round 5
// 239.268 us; speedup vs baseline: 1.0176x; 1.0176x over previous
//
#include <hip/hip_runtime.h>

// CSPN propagation step, row-per-wave, register-only, occupancy-tuned.
// out[b,0,y,x] = sum_{k!=4} aff[b,k,y,x]*cur[b,0,y+dy-1,x+dx-1] (zero pad)
//              + aff[b,4,y,x]*coarse[b,0,y,x],   k = dy*3+dx.
//
// W=512 = 64 lanes * 8 px: one wave per row; x-halos via __shfl, shifted
// windows via shufflevector. __launch_bounds__(256,4) caps VGPRs (~128) so
// >=4 waves/SIMD stay resident; affinity loads interleaved with FMAs to
// keep the live set under the cap without spilling.

typedef float f8 __attribute__((ext_vector_type(8)));

constexpr int Bc = 16, Hc = 512, Wc = 512;

__global__ __launch_bounds__(256, 4) void cspn_kernel(
    const float* __restrict__ aff,
    const float* __restrict__ cur,
    const float* __restrict__ coarse,
    float* __restrict__ out)
{
    const int lane  = threadIdx.x & 63;
    const int row   = (blockIdx.x << 2) + (threadIdx.x >> 6);  // 0..B*H-1
    const int y     = row & (Hc - 1);
    const int b     = row >> 9;                                // row / H
    const int plane = Hc * Wc;
    const int rb    = row * Wc;                                // b*plane + y*W
    const int xo    = lane << 3;                               // 8 px per lane

    const float* curp = cur + rb + xo;
    const float* ab   = aff + b * 9 * plane + y * Wc + xo;

    // Issue source-row loads first (latency-critical: feed the shuffles)
    f8 mm = *(const f8*)curp;
    f8 um = (f8)(0.f), dm = (f8)(0.f);
    if (y > 0)      um = *(const f8*)(curp - Wc);
    if (y < Hc - 1) dm = *(const f8*)(curp + Wc);
    f8 cm = *(const f8*)(coarse + rb + xo);

    // First few affinity channels in flight while shuffles run
    f8 a0 = __builtin_nontemporal_load((const f8*)(ab + 0 * plane));
    f8 a1 = __builtin_nontemporal_load((const f8*)(ab + 1 * plane));
    f8 a2 = __builtin_nontemporal_load((const f8*)(ab + 2 * plane));

    // x-halos from neighbor lanes (zero at image borders)
    float uL = __shfl_up(um.s7, 1), mL = __shfl_up(mm.s7, 1), dL = __shfl_up(dm.s7, 1);
    float uR = __shfl_down(um.s0, 1), mR = __shfl_down(mm.s0, 1), dR = __shfl_down(dm.s0, 1);
    if (lane == 0)  { uL = 0.f; mL = 0.f; dL = 0.f; }
    if (lane == 63) { uR = 0.f; mR = 0.f; dR = 0.f; }

    // Shifted windows in registers: l = [halo, v0..v6], r = [v1..v7, halo]
    f8 ul = __builtin_shufflevector(um, um, 7,0,1,2,3,4,5,6); ul.s0 = uL;
    f8 ur = __builtin_shufflevector(um, um, 1,2,3,4,5,6,7,0); ur.s7 = uR;

    f8 acc = a0 * ul;
    acc += a1 * um;
    acc += a2 * ur;

    f8 a3 = __builtin_nontemporal_load((const f8*)(ab + 3 * plane));
    f8 a4 = __builtin_nontemporal_load((const f8*)(ab + 4 * plane));
    f8 a5 = __builtin_nontemporal_load((const f8*)(ab + 5 * plane));

    f8 ml = __builtin_shufflevector(mm, mm, 7,0,1,2,3,4,5,6); ml.s0 = mL;
    f8 mr = __builtin_shufflevector(mm, mm, 1,2,3,4,5,6,7,0); mr.s7 = mR;

    acc += a3 * ml;
    acc += a4 * cm;   // center tap -> coarse_seg
    acc += a5 * mr;

    f8 a6 = __builtin_nontemporal_load((const f8*)(ab + 6 * plane));
    f8 a7 = __builtin_nontemporal_load((const f8*)(ab + 7 * plane));
    f8 a8 = __builtin_nontemporal_load((const f8*)(ab + 8 * plane));

    f8 dl = __builtin_shufflevector(dm, dm, 7,0,1,2,3,4,5,6); dl.s0 = dL;
    f8 dr = __builtin_shufflevector(dm, dm, 1,2,3,4,5,6,7,0); dr.s7 = dR;

    acc += a6 * dl;
    acc += a7 * dm;
    acc += a8 * dr;

    __builtin_nontemporal_store(acc, (f8*)(out + rb + xo));
}

extern "C" void kernel_launch(void* const* d_in, const int* in_sizes, int n_in,
                              void* d_out, int out_size, void* d_ws, size_t ws_size,
                              hipStream_t stream) {
    const float* aff    = (const float*)d_in[0];  // [16, 9, 512, 512]
    const float* cur    = (const float*)d_in[1];  // [16, 1, 512, 512]
    const float* coarse = (const float*)d_in[2];  // [16, 1, 512, 512]
    float* out = (float*)d_out;                   // [16, 1, 512, 512]

    const int rows  = Bc * Hc;      // 8192 rows, one wave each
    const int block = 256;          // 4 waves per block
    const int grid  = rows / 4;     // 2048 blocks

    cspn_kernel<<<grid, block, 0, stream>>>(aff, cur, coarse, out);
}